// Round 3
// baseline (150.194 us; speedup 1.0000x reference)
//
#include <hip/hip_runtime.h>
#include <math.h>

// Problem constants (from reference)
#define NCAMS 48      // B*NC = 8*6
#define NC_   6
#define A_    25200
#define C_    10
#define MAXGT 32
#define L_COORD 5.0f
#define L_NOOBJ 0.5f

// 4 anchors/thread, slim registers (~55 VGPR target, enforced via
// __launch_bounds__(256,8) -> <=64 VGPR -> 32 waves/CU). Rationale: the
// per-k LDS broadcast reads (b128+b32 per GT) are per-THREAD regardless of
// anchors-per-thread, so APT=4 halves total LDS issue + wave overhead vs
// APT=2. Round-1's APT=4 failure was confounded by fences + VGPR=84.
#define BLOCK  256
#define APT    4
#define CHUNK  (BLOCK * APT)                 // 1024 anchors per block
#define NCHUNK ((A_ + CHUNK - 1) / CHUNK)    // 25
#define NBLK   (NCHUNK * NCAMS)              // 1200

__device__ __forceinline__ float softplus_f(float x) {
    return fmaxf(x, 0.0f) + log1pf(expf(-fabsf(x)));
}

// Phase 1: per (cam, anchor-chunk) block -> 6 partial sums.
__global__ __launch_bounds__(BLOCK, 8)
void yolo_phase1(const float* __restrict__ pred_boxes,   // (cams, A, 4)
                 const float* __restrict__ pred_labels,  // (cams, A, C)
                 const float* __restrict__ pred_obj,     // (cams, A, 1)
                 const float* __restrict__ gt_boxes,     // (TG, 4) cxcywh
                 const int*   __restrict__ gt_labels,    // (TG)
                 const int*   __restrict__ se,           // (B, NC)
                 int total_gt,
                 float* __restrict__ partials)           // (cams*NCHUNK, 8)
{
    const int cam   = blockIdx.y;
    const int chunk = blockIdx.x;
    const int tid   = threadIdx.x;

    __shared__ float4 s_corner[MAXGT];   // g1x, g1y, g2x, g2y
    __shared__ float4 s_orig[MAXGT];     // cx, cy, w, h (rare-path box SE)
    __shared__ float  s_area[MAXGT];
    __shared__ int    s_lbl[MAXGT];
    __shared__ float  s_red[BLOCK / 64][6];

    const int b  = cam / NC_;
    const int nc = cam - b * NC_;
    int off = 0;
    for (int bb = 0; bb < b; ++bb) off += se[bb * NC_ + (NC_ - 1)];
    const int start = off + (nc ? se[b * NC_ + nc - 1] : 0);
    const int end   = off + se[b * NC_ + nc];
    int ngt = end - start;
    if (ngt < 0) ngt = 0;
    if (ngt > MAXGT) ngt = MAXGT;

    if (tid < ngt) {
        int gi = start + tid;
        gi = min(max(gi, 0), total_gt - 1);   // reference clips gidx
        float4 gb = ((const float4*)gt_boxes)[gi];
        float hw = gb.z * 0.5f, hh = gb.w * 0.5f;
        s_corner[tid] = make_float4(gb.x - hw, gb.y - hh, gb.x + hw, gb.y + hh);
        s_orig[tid]   = gb;
        s_area[tid]   = gb.z * gb.w;
        s_lbl[tid]    = gt_labels[gi];
    }
    __syncthreads();

    const int base = chunk * CHUNK;
    const float4* pb4 = (const float4*)pred_boxes;

    // Slim per-anchor state: 8 floats + 1 int. pred_boxes is reloaded from
    // cache in the (rare, ~0.08%) positive path instead of held in VGPRs.
    float p1x[APT], p1y[APT], p2x[APT], p2y[APT], pa[APT];
    float bi[APT], db[APT], o[APT];   // best (inter, denom); iou = bi/db
    int   bk[APT];

    #pragma unroll
    for (int i = 0; i < APT; ++i) {
        int a  = base + i * BLOCK + tid;
        int ac = (a < A_) ? a : (A_ - 1);
        int idx = cam * A_ + ac;             // < 1.21e6, fits int
        float4 p = pb4[idx];
        o[i]  = pred_obj[idx];
        p1x[i] = p.x - p.z * 0.5f;
        p1y[i] = p.y - p.w * 0.5f;
        p2x[i] = p.x + p.z * 0.5f;
        p2y[i] = p.y + p.w * 0.5f;
        pa[i]  = p.z * p.w + 1e-6f;          // folds reference's +1e-6
        bi[i]  = -1.0f;                      // ngt==0 -> iou=-1 -> negative
        db[i]  = 1.0f;
        bk[i]  = 0;
    }

    // argmax IoU via cross-multiplication: a/b > c/d <=> a*d > c*b (b,d > 0).
    // No v_rcp; strict '>' with ascending k == jnp.argmax (first max).
    auto iou_step = [&](int k) {
        const float4 g  = s_corner[k];
        const float  ga = s_area[k];
        #pragma unroll
        for (int i = 0; i < APT; ++i) {
            float wx = fmaxf(fminf(p2x[i], g.z) - fmaxf(p1x[i], g.x), 0.0f);
            float wy = fmaxf(fminf(p2y[i], g.w) - fmaxf(p1y[i], g.y), 0.0f);
            float inter = wx * wy;
            float den   = pa[i] + (ga - inter);        // union + 1e-6 > 0
            if (inter * db[i] > bi[i] * den) {
                bi[i] = inter; db[i] = den; bk[i] = k;
            }
        }
    };

    if (ngt == 20) {                 // hot path in this dataset: full unroll
        #pragma unroll
        for (int k = 0; k < 20; ++k) iou_step(k);
    } else {
        for (int k = 0; k < ngt; ++k) iou_step(k);
    }

    float pos_cnt = 0.f, neg_cnt = 0.f;
    float box_acc = 0.f, spp_acc = 0.f, spn_acc = 0.f, ce_acc = 0.f;

    #pragma unroll
    for (int i = 0; i < APT; ++i) {
        int a = base + i * BLOCK + tid;
        if (a >= A_) continue;
        // pos <=> best_iou > 0.5 <=> bi > 0.5*db (0.5*db exact)
        if (bi[i] > 0.5f * db[i]) {
            pos_cnt += 1.0f;
            const int idx = cam * A_ + a;
            const float4 p  = pb4[idx];          // cache-hot reload, rare
            const float4 mb = s_orig[bk[i]];
            const float dx = p.x - mb.x, dy = p.y - mb.y;
            const float dz = p.z - mb.z, dw = p.w - mb.w;
            box_acc += dx * dx + dy * dy + dz * dz + dw * dw;
            spp_acc += softplus_f(-o[i]);
            const float* lg = pred_labels + (size_t)idx * C_;
            float m = lg[0];
            #pragma unroll
            for (int j = 1; j < C_; ++j) m = fmaxf(m, lg[j]);
            float sexp = 0.f;
            #pragma unroll
            for (int j = 0; j < C_; ++j) sexp += expf(lg[j] - m);
            ce_acc += -(lg[s_lbl[bk[i]]] - m - logf(sexp));
        } else {
            neg_cnt += 1.0f;
            spn_acc += softplus_f(o[i]);
        }
    }

    // block reduction of 6 values
    float v[6] = {pos_cnt, neg_cnt, box_acc, spp_acc, spn_acc, ce_acc};
    #pragma unroll
    for (int i = 0; i < 6; ++i) {
        float x = v[i];
        for (int s = 32; s; s >>= 1) x += __shfl_down(x, s, 64);
        v[i] = x;
    }
    if ((tid & 63) == 0) {
        const int w = tid >> 6;
        #pragma unroll
        for (int i = 0; i < 6; ++i) s_red[w][i] = v[i];
    }
    __syncthreads();
    if (tid == 0) {
        float s0 = s_red[0][0] + s_red[1][0] + s_red[2][0] + s_red[3][0];
        float s1 = s_red[0][1] + s_red[1][1] + s_red[2][1] + s_red[3][1];
        float s2 = s_red[0][2] + s_red[1][2] + s_red[2][2] + s_red[3][2];
        float s3 = s_red[0][3] + s_red[1][3] + s_red[2][3] + s_red[3][3];
        float s4 = s_red[0][4] + s_red[1][4] + s_red[2][4] + s_red[3][4];
        float s5 = s_red[0][5] + s_red[1][5] + s_red[2][5] + s_red[3][5];
        float4* outp = (float4*)(partials + (size_t)(cam * NCHUNK + chunk) * 8);
        outp[0] = make_float4(s0, s1, s2, s3);
        outp[1] = make_float4(s4, s5, 0.f, 0.f);
    }
}

// Phase 2: 240 threads (5 per cam, 5 records each, float4 loads) -> LDS
// reduce -> wave-0 shuffle reduce.
#define TPC 5
#define RPT (NCHUNK / TPC)    // 5
__global__ void yolo_phase2(const float* __restrict__ partials,
                            float* __restrict__ out)
{
    const int t = threadIdx.x;   // 0..255
    __shared__ float s_p[NCAMS * TPC][6];

    if (t < NCAMS * TPC) {
        const int cam = t / TPC;
        const int j   = t - cam * TPC;
        const float4* q = (const float4*)(partials +
                          ((size_t)cam * NCHUNK + j * RPT) * 8);
        float a0 = 0.f, a1 = 0.f, a2 = 0.f, a3 = 0.f, a4 = 0.f, a5 = 0.f;
        #pragma unroll
        for (int i = 0; i < RPT; ++i) {
            float4 x = q[2 * i];
            float4 y = q[2 * i + 1];
            a0 += x.x; a1 += x.y; a2 += x.z; a3 += x.w;
            a4 += y.x; a5 += y.y;
        }
        s_p[t][0] = a0; s_p[t][1] = a1; s_p[t][2] = a2;
        s_p[t][3] = a3; s_p[t][4] = a4; s_p[t][5] = a5;
    }
    __syncthreads();

    float box_sum = 0.f, obj_sum = 0.f, noobj_sum = 0.f, cls_sum = 0.f;
    float np_ = 0.f, nn_ = 0.f;
    if (t < NCAMS) {
        float p = 0.f, n = 0.f, bx = 0.f, sp = 0.f, sn = 0.f, ce = 0.f;
        #pragma unroll
        for (int j = 0; j < TPC; ++j) {
            p  += s_p[t * TPC + j][0];
            n  += s_p[t * TPC + j][1];
            bx += s_p[t * TPC + j][2];
            sp += s_p[t * TPC + j][3];
            sn += s_p[t * TPC + j][4];
            ce += s_p[t * TPC + j][5];
        }
        box_sum   = L_COORD * bx;
        obj_sum   = (p > 0.f) ? sp / fmaxf(p, 1.0f) : 0.f;
        cls_sum   = (p > 0.f) ? ce / fmaxf(p, 1.0f) : 0.f;
        noobj_sum = L_NOOBJ * ((n > 0.f) ? sn / fmaxf(n, 1.0f) : 0.f);
        np_ = p; nn_ = n;
    }
    if (t < 64) {   // cams 0..47 all live in wave 0
        for (int s = 32; s; s >>= 1) {
            box_sum   += __shfl_down(box_sum, s, 64);
            obj_sum   += __shfl_down(obj_sum, s, 64);
            noobj_sum += __shfl_down(noobj_sum, s, 64);
            cls_sum   += __shfl_down(cls_sum, s, 64);
            np_       += __shfl_down(np_, s, 64);
            nn_       += __shfl_down(nn_, s, 64);
        }
        if (t == 0) {
            const float box_loss   = (np_ > 0.f) ? box_sum / fmaxf(np_, 1.0f) : 0.f;
            const float obj_loss   = (np_ > 0.f) ? obj_sum / fmaxf(np_, 1.0f) : 0.f;
            const float cls_loss   = (np_ > 0.f) ? cls_sum / fmaxf(np_, 1.0f) : 0.f;
            const float noobj_loss = (nn_ > 0.f) ? noobj_sum / fmaxf(nn_, 1.0f) : 0.f;
            const float total = box_loss + obj_loss + noobj_loss + cls_loss;
            out[0] = total;
            out[1] = box_loss;
            out[2] = obj_loss;
            out[3] = noobj_loss;
            out[4] = cls_loss;
        }
    }
}

extern "C" void kernel_launch(void* const* d_in, const int* in_sizes, int n_in,
                              void* d_out, int out_size, void* d_ws, size_t ws_size,
                              hipStream_t stream) {
    const float* pred_boxes  = (const float*)d_in[0];
    const float* pred_labels = (const float*)d_in[1];
    const float* pred_obj    = (const float*)d_in[2];
    const float* gt_boxes    = (const float*)d_in[3];
    const int*   gt_labels   = (const int*)d_in[4];
    const int*   se          = (const int*)d_in[5];
    const int total_gt = in_sizes[3] / 4;

    float* partials = (float*)d_ws;   // NCAMS*NCHUNK*8 floats = 38.4 KB

    dim3 grid(NCHUNK, NCAMS);
    yolo_phase1<<<grid, BLOCK, 0, stream>>>(pred_boxes, pred_labels, pred_obj,
                                            gt_boxes, gt_labels, se,
                                            total_gt, partials);
    yolo_phase2<<<1, 256, 0, stream>>>(partials, (float*)d_out);
}

// Round 4
// 127.889 us; speedup vs baseline: 1.1744x; 1.1744x over previous
//
#include <hip/hip_runtime.h>
#include <math.h>

// Problem constants (from reference)
#define NCAMS 48      // B*NC = 8*6
#define NC_   6
#define A_    25200
#define C_    10
#define MAXGT 32
#define L_COORD 5.0f
#define L_NOOBJ 0.5f

// 4 contiguous anchors/thread -> 1200 blocks (4800 waves = 18.75 waves/CU
// demanded). Slim per-anchor state (~9 regs) targets VGPR <= 64 naturally.
// NO min-waves launch_bounds clamp: round-3 showed (256,8) forces VGPR=32 ->
// catastrophic scratch spills (WRITE_SIZE 109 MB, 2.5x slowdown).
#define BLOCK  256
#define APT    4
#define CHUNK  (BLOCK * APT)                 // 1024 anchors per block
#define NCHUNK ((A_ + CHUNK - 1) / CHUNK)    // 25

__device__ __forceinline__ float softplus_f(float x) {
    return fmaxf(x, 0.0f) + log1pf(expf(-fabsf(x)));
}

// Phase 1: per (cam, anchor-chunk) block -> 6 partial sums.
__global__ __launch_bounds__(BLOCK)
void yolo_phase1(const float* __restrict__ pred_boxes,   // (cams, A, 4)
                 const float* __restrict__ pred_labels,  // (cams, A, C)
                 const float* __restrict__ pred_obj,     // (cams, A, 1)
                 const float* __restrict__ gt_boxes,     // (TG, 4) cxcywh
                 const int*   __restrict__ gt_labels,    // (TG)
                 const int*   __restrict__ se,           // (B, NC)
                 int total_gt,
                 float* __restrict__ partials)           // (cams*NCHUNK, 8)
{
    const int cam   = blockIdx.y;
    const int chunk = blockIdx.x;
    const int tid   = threadIdx.x;

    __shared__ float4 s_corner[MAXGT];   // g1x, g1y, g2x, g2y
    __shared__ float4 s_orig[MAXGT];     // cx, cy, w, h (rare-path box SE)
    __shared__ float  s_area[MAXGT];
    __shared__ int    s_lbl[MAXGT];
    __shared__ float  s_red[BLOCK / 64][6];

    const int b  = cam / NC_;
    const int nc = cam - b * NC_;
    int off = 0;
    for (int bb = 0; bb < b; ++bb) off += se[bb * NC_ + (NC_ - 1)];
    const int start = off + (nc ? se[b * NC_ + nc - 1] : 0);
    const int end   = off + se[b * NC_ + nc];
    int ngt = end - start;
    if (ngt < 0) ngt = 0;
    if (ngt > MAXGT) ngt = MAXGT;

    if (tid < ngt) {
        int gi = start + tid;
        gi = min(max(gi, 0), total_gt - 1);   // reference clips gidx
        float4 gb = ((const float4*)gt_boxes)[gi];
        float hw = gb.z * 0.5f, hh = gb.w * 0.5f;
        s_corner[tid] = make_float4(gb.x - hw, gb.y - hh, gb.x + hw, gb.y + hh);
        s_orig[tid]   = gb;
        s_area[tid]   = gb.z * gb.w;
        s_lbl[tid]    = gt_labels[gi];
    }
    __syncthreads();

    // Contiguous 4-anchor ownership: thread t -> anchors base+4t .. base+4t+3.
    // pred_obj: one float4 (16 B/lane, wave covers 1 KB contiguous).
    // pred_boxes: 4x float4 (64 B/lane contiguous).
    const int base = chunk * CHUNK;
    const int a0   = base + tid * APT;
    const float4* pb4 = (const float4*)pred_boxes;

    float4 ov;
    {
        // Last chunk: a0 may exceed A_-4; clamp the float4 base so the load
        // stays in bounds (A_ % 4 == 0, so clamped load is aligned & legal).
        int aoc = (a0 <= A_ - APT) ? a0 : (A_ - APT);
        ov = *(const float4*)(pred_obj + (size_t)cam * A_ + aoc);
        if (a0 != aoc) {
            // shift so o[i] aligns with anchor a0+i where possible (invalid
            // lanes are skipped in the epilogue anyway; values don't matter)
        }
    }
    const float o[APT] = {ov.x, ov.y, ov.z, ov.w};

    // Slim per-anchor state: 9 regs. pred_boxes reloaded (cache-hot) in the
    // rare (~0.08%) positive path instead of held in VGPRs.
    float p1x[APT], p1y[APT], p2x[APT], p2y[APT], pa[APT];
    float bi[APT], db[APT];              // best (inter, denom); iou = bi/db
    int   bk[APT];

    #pragma unroll
    for (int i = 0; i < APT; ++i) {
        int a  = a0 + i;
        int ac = (a < A_) ? a : (A_ - 1);
        float4 p = pb4[(size_t)cam * A_ + ac];
        p1x[i] = p.x - p.z * 0.5f;
        p1y[i] = p.y - p.w * 0.5f;
        p2x[i] = p.x + p.z * 0.5f;
        p2y[i] = p.y + p.w * 0.5f;
        pa[i]  = p.z * p.w + 1e-6f;          // folds reference's +1e-6
        bi[i]  = -1.0f;                      // ngt==0 -> iou=-1 -> negative
        db[i]  = 1.0f;
        bk[i]  = 0;
    }

    // argmax IoU via cross-multiplication: a/b > c/d <=> a*d > c*b (b,d > 0).
    // No v_rcp; strict '>' with ascending k == jnp.argmax (first max).
    auto iou_step = [&](int k) {
        const float4 g  = s_corner[k];
        const float  ga = s_area[k];
        #pragma unroll
        for (int i = 0; i < APT; ++i) {
            float wx = fmaxf(fminf(p2x[i], g.z) - fmaxf(p1x[i], g.x), 0.0f);
            float wy = fmaxf(fminf(p2y[i], g.w) - fmaxf(p1y[i], g.y), 0.0f);
            float inter = wx * wy;
            float den   = pa[i] + (ga - inter);        // union + 1e-6 > 0
            if (inter * db[i] > bi[i] * den) {
                bi[i] = inter; db[i] = den; bk[i] = k;
            }
        }
    };

    if (ngt == 20) {                 // hot path in this dataset: full unroll
        #pragma unroll
        for (int k = 0; k < 20; ++k) iou_step(k);
    } else {
        for (int k = 0; k < ngt; ++k) iou_step(k);
    }

    float pos_cnt = 0.f, neg_cnt = 0.f;
    float box_acc = 0.f, spp_acc = 0.f, spn_acc = 0.f, ce_acc = 0.f;

    #pragma unroll
    for (int i = 0; i < APT; ++i) {
        int a = a0 + i;
        if (a >= A_) continue;
        // o[i] corresponds to anchor a0+i only when the float4 base wasn't
        // clamped; when it was (last partial thread), remap index:
        float oi = o[i];
        if (a0 > A_ - APT) oi = ((const float*)&o[0])[a - (A_ - APT)];
        // pos <=> best_iou > 0.5 <=> bi > 0.5*db (0.5*db exact)
        if (bi[i] > 0.5f * db[i]) {
            pos_cnt += 1.0f;
            const int idx = cam * A_ + a;
            const float4 p  = pb4[idx];          // cache-hot reload, rare
            const float4 mb = s_orig[bk[i]];
            const float dx = p.x - mb.x, dy = p.y - mb.y;
            const float dz = p.z - mb.z, dw = p.w - mb.w;
            box_acc += dx * dx + dy * dy + dz * dz + dw * dw;
            spp_acc += softplus_f(-oi);
            const float* lg = pred_labels + (size_t)idx * C_;
            float m = lg[0];
            #pragma unroll
            for (int j = 1; j < C_; ++j) m = fmaxf(m, lg[j]);
            float sexp = 0.f;
            #pragma unroll
            for (int j = 0; j < C_; ++j) sexp += expf(lg[j] - m);
            ce_acc += -(lg[s_lbl[bk[i]]] - m - logf(sexp));
        } else {
            neg_cnt += 1.0f;
            spn_acc += softplus_f(oi);
        }
    }

    // block reduction of 6 values
    float v[6] = {pos_cnt, neg_cnt, box_acc, spp_acc, spn_acc, ce_acc};
    #pragma unroll
    for (int i = 0; i < 6; ++i) {
        float x = v[i];
        for (int s = 32; s; s >>= 1) x += __shfl_down(x, s, 64);
        v[i] = x;
    }
    if ((tid & 63) == 0) {
        const int w = tid >> 6;
        #pragma unroll
        for (int i = 0; i < 6; ++i) s_red[w][i] = v[i];
    }
    __syncthreads();
    if (tid == 0) {
        float s0 = s_red[0][0] + s_red[1][0] + s_red[2][0] + s_red[3][0];
        float s1 = s_red[0][1] + s_red[1][1] + s_red[2][1] + s_red[3][1];
        float s2 = s_red[0][2] + s_red[1][2] + s_red[2][2] + s_red[3][2];
        float s3 = s_red[0][3] + s_red[1][3] + s_red[2][3] + s_red[3][3];
        float s4 = s_red[0][4] + s_red[1][4] + s_red[2][4] + s_red[3][4];
        float s5 = s_red[0][5] + s_red[1][5] + s_red[2][5] + s_red[3][5];
        float4* outp = (float4*)(partials + (size_t)(cam * NCHUNK + chunk) * 8);
        outp[0] = make_float4(s0, s1, s2, s3);
        outp[1] = make_float4(s4, s5, 0.f, 0.f);
    }
}

// Phase 2: 240 threads (5 per cam, 5 records each, float4 loads) -> LDS
// reduce -> wave-0 shuffle reduce.
#define TPC 5
#define RPT (NCHUNK / TPC)    // 5
__global__ void yolo_phase2(const float* __restrict__ partials,
                            float* __restrict__ out)
{
    const int t = threadIdx.x;   // 0..255
    __shared__ float s_p[NCAMS * TPC][6];

    if (t < NCAMS * TPC) {
        const int cam = t / TPC;
        const int j   = t - cam * TPC;
        const float4* q = (const float4*)(partials +
                          ((size_t)cam * NCHUNK + j * RPT) * 8);
        float a0 = 0.f, a1 = 0.f, a2 = 0.f, a3 = 0.f, a4 = 0.f, a5 = 0.f;
        #pragma unroll
        for (int i = 0; i < RPT; ++i) {
            float4 x = q[2 * i];
            float4 y = q[2 * i + 1];
            a0 += x.x; a1 += x.y; a2 += x.z; a3 += x.w;
            a4 += y.x; a5 += y.y;
        }
        s_p[t][0] = a0; s_p[t][1] = a1; s_p[t][2] = a2;
        s_p[t][3] = a3; s_p[t][4] = a4; s_p[t][5] = a5;
    }
    __syncthreads();

    float box_sum = 0.f, obj_sum = 0.f, noobj_sum = 0.f, cls_sum = 0.f;
    float np_ = 0.f, nn_ = 0.f;
    if (t < NCAMS) {
        float p = 0.f, n = 0.f, bx = 0.f, sp = 0.f, sn = 0.f, ce = 0.f;
        #pragma unroll
        for (int j = 0; j < TPC; ++j) {
            p  += s_p[t * TPC + j][0];
            n  += s_p[t * TPC + j][1];
            bx += s_p[t * TPC + j][2];
            sp += s_p[t * TPC + j][3];
            sn += s_p[t * TPC + j][4];
            ce += s_p[t * TPC + j][5];
        }
        box_sum   = L_COORD * bx;
        obj_sum   = (p > 0.f) ? sp / fmaxf(p, 1.0f) : 0.f;
        cls_sum   = (p > 0.f) ? ce / fmaxf(p, 1.0f) : 0.f;
        noobj_sum = L_NOOBJ * ((n > 0.f) ? sn / fmaxf(n, 1.0f) : 0.f);
        np_ = p; nn_ = n;
    }
    if (t < 64) {   // cams 0..47 all live in wave 0
        for (int s = 32; s; s >>= 1) {
            box_sum   += __shfl_down(box_sum, s, 64);
            obj_sum   += __shfl_down(obj_sum, s, 64);
            noobj_sum += __shfl_down(noobj_sum, s, 64);
            cls_sum   += __shfl_down(cls_sum, s, 64);
            np_       += __shfl_down(np_, s, 64);
            nn_       += __shfl_down(nn_, s, 64);
        }
        if (t == 0) {
            const float box_loss   = (np_ > 0.f) ? box_sum / fmaxf(np_, 1.0f) : 0.f;
            const float obj_loss   = (np_ > 0.f) ? obj_sum / fmaxf(np_, 1.0f) : 0.f;
            const float cls_loss   = (np_ > 0.f) ? cls_sum / fmaxf(np_, 1.0f) : 0.f;
            const float noobj_loss = (nn_ > 0.f) ? noobj_sum / fmaxf(nn_, 1.0f) : 0.f;
            const float total = box_loss + obj_loss + noobj_loss + cls_loss;
            out[0] = total;
            out[1] = box_loss;
            out[2] = obj_loss;
            out[3] = noobj_loss;
            out[4] = cls_loss;
        }
    }
}

extern "C" void kernel_launch(void* const* d_in, const int* in_sizes, int n_in,
                              void* d_out, int out_size, void* d_ws, size_t ws_size,
                              hipStream_t stream) {
    const float* pred_boxes  = (const float*)d_in[0];
    const float* pred_labels = (const float*)d_in[1];
    const float* pred_obj    = (const float*)d_in[2];
    const float* gt_boxes    = (const float*)d_in[3];
    const int*   gt_labels   = (const int*)d_in[4];
    const int*   se          = (const int*)d_in[5];
    const int total_gt = in_sizes[3] / 4;

    float* partials = (float*)d_ws;   // NCAMS*NCHUNK*8 floats = 38.4 KB

    dim3 grid(NCHUNK, NCAMS);
    yolo_phase1<<<grid, BLOCK, 0, stream>>>(pred_boxes, pred_labels, pred_obj,
                                            gt_boxes, gt_labels, se,
                                            total_gt, partials);
    yolo_phase2<<<1, 256, 0, stream>>>(partials, (float*)d_out);
}

// Round 5
// 123.099 us; speedup vs baseline: 1.2201x; 1.0389x over previous
//
#include <hip/hip_runtime.h>
#include <math.h>

// Problem constants (from reference)
#define NCAMS 48      // B*NC = 8*6
#define NC_   6
#define A_    25200
#define C_    10
#define MAXGT 32
#define L_COORD 5.0f
#define L_NOOBJ 0.5f

// 2 anchors/thread -> 2400 blocks. block=256: 4 waves/block. Measured optimum
// across APT={2,4} x {fused,two-phase} x {clamp,no-clamp} (rounds 0-4):
// APT=2 two-phase = 123.8 us. APT=4 (clean, R4) = 127.9: fewer waves -> less
// TLP for the dependent argmax chain. (256,8) clamp -> VGPR=32 spills (R3).
// Per-block device-scope fences -> ~2x serialization (R1).
#define BLOCK  256
#define CHUNK  (BLOCK * 2)                   // 512 anchors per block
#define NCHUNK ((A_ + CHUNK - 1) / CHUNK)    // 50

__device__ __forceinline__ float softplus_f(float x) {
    return fmaxf(x, 0.0f) + log1pf(expf(-fabsf(x)));
}

// Phase 1: per (cam, anchor-chunk) block -> 6 partial sums.
__global__ __launch_bounds__(BLOCK)
void yolo_phase1(const float* __restrict__ pred_boxes,   // (cams, A, 4)
                 const float* __restrict__ pred_labels,  // (cams, A, C)
                 const float* __restrict__ pred_obj,     // (cams, A, 1)
                 const float* __restrict__ gt_boxes,     // (TG, 4) cxcywh
                 const int*   __restrict__ gt_labels,    // (TG)
                 const int*   __restrict__ se,           // (B, NC)
                 int total_gt,
                 float* __restrict__ partials)           // (cams*NCHUNK, 8)
{
    const int cam   = blockIdx.y;
    const int chunk = blockIdx.x;
    const int tid   = threadIdx.x;

    __shared__ float4 s_corner[MAXGT];   // g1x, g1y, g2x, g2y
    __shared__ float4 s_orig[MAXGT];     // cx, cy, w, h (for box SE)
    __shared__ float  s_area[MAXGT];
    __shared__ int    s_lbl[MAXGT];
    __shared__ float  s_red[BLOCK / 64][6];

    const int b  = cam / NC_;
    const int nc = cam - b * NC_;
    int off = 0;
    for (int bb = 0; bb < b; ++bb) off += se[bb * NC_ + (NC_ - 1)];
    const int start = off + (nc ? se[b * NC_ + nc - 1] : 0);
    const int end   = off + se[b * NC_ + nc];
    int ngt = end - start;
    if (ngt < 0) ngt = 0;
    if (ngt > MAXGT) ngt = MAXGT;

    if (tid < ngt) {
        int gi = start + tid;
        gi = min(max(gi, 0), total_gt - 1);   // reference clips gidx
        float4 gb = ((const float4*)gt_boxes)[gi];
        float hw = gb.z * 0.5f, hh = gb.w * 0.5f;
        s_corner[tid] = make_float4(gb.x - hw, gb.y - hh, gb.x + hw, gb.y + hh);
        s_orig[tid]   = gb;
        s_area[tid]   = gb.z * gb.w;
        s_lbl[tid]    = gt_labels[gi];
    }
    __syncthreads();

    const int base = chunk * CHUNK;
    const int a0 = base + tid;
    const int a1 = base + BLOCK + tid;
    const bool valid0 = (a0 < A_);
    const bool valid1 = (a1 < A_);
    const int a0c = valid0 ? a0 : (A_ - 1);
    const int a1c = valid1 ? a1 : (A_ - 1);
    const int idx0 = cam * A_ + a0c;     // < 1.21e6, fits int
    const int idx1 = cam * A_ + a1c;

    const float4* pb4 = (const float4*)pred_boxes;
    const float4 p0 = pb4[idx0];
    const float4 p1 = pb4[idx1];
    const float o0 = pred_obj[idx0];     // load early, used after k-loop
    const float o1 = pred_obj[idx1];

    const float p1x0 = p0.x - p0.z * 0.5f, p1y0 = p0.y - p0.w * 0.5f;
    const float p2x0 = p0.x + p0.z * 0.5f, p2y0 = p0.y + p0.w * 0.5f;
    const float pa0  = p0.z * p0.w + 1e-6f;
    const float p1x1 = p1.x - p1.z * 0.5f, p1y1 = p1.y - p1.w * 0.5f;
    const float p2x1 = p1.x + p1.z * 0.5f, p2y1 = p1.y + p1.w * 0.5f;
    const float pa1  = p1.z * p1.w + 1e-6f;

    // argmax IoU via cross-multiplication: a/b > c/d <=> a*d > c*b (b,d > 0).
    // No v_rcp in the loop; strict '>' with ascending k == jnp.argmax (first max).
    float bi0 = -1.0f, db0 = 1.0f, bi1 = -1.0f, db1 = 1.0f;
    int bk0 = 0, bk1 = 0;

    auto iou_step = [&](int k) {
        const float4 g  = s_corner[k];
        const float  ga = s_area[k];
        float wx0 = fmaxf(fminf(p2x0, g.z) - fmaxf(p1x0, g.x), 0.0f);
        float wy0 = fmaxf(fminf(p2y0, g.w) - fmaxf(p1y0, g.y), 0.0f);
        float wx1 = fmaxf(fminf(p2x1, g.z) - fmaxf(p1x1, g.x), 0.0f);
        float wy1 = fmaxf(fminf(p2y1, g.w) - fmaxf(p1y1, g.y), 0.0f);
        const float inter0 = wx0 * wy0;
        const float inter1 = wx1 * wy1;
        const float den0   = pa0 + (ga - inter0);   // union + 1e-6 > 0
        const float den1   = pa1 + (ga - inter1);
        if (inter0 * db0 > bi0 * den0) { bi0 = inter0; db0 = den0; bk0 = k; }
        if (inter1 * db1 > bi1 * den1) { bi1 = inter1; db1 = den1; bk1 = k; }
    };

    if (ngt == 20) {                 // hot path in this dataset: full unroll
        #pragma unroll
        for (int k = 0; k < 20; ++k) iou_step(k);
    } else {
        for (int k = 0; k < ngt; ++k) iou_step(k);
    }

    float pos_cnt = 0.f, neg_cnt = 0.f;
    float box_acc = 0.f, spp_acc = 0.f, spn_acc = 0.f, ce_acc = 0.f;

    auto accumulate = [&](bool valid, float bi, float db, int bk,
                          const float4& p, float o, int idx) {
        if (!valid) return;
        // pos <=> best_iou > 0.5 <=> bi > 0.5*db (ngt==0 -> bi=-1 -> negative)
        if (bi > 0.5f * db) {
            pos_cnt += 1.0f;
            const float4 mb = s_orig[bk];
            const float dx = p.x - mb.x, dy = p.y - mb.y;
            const float dz = p.z - mb.z, dw = p.w - mb.w;
            box_acc += dx * dx + dy * dy + dz * dz + dw * dw;
            spp_acc += softplus_f(-o);
            const float* lg = pred_labels + (size_t)idx * C_;  // rare path
            float m = lg[0];
            #pragma unroll
            for (int i = 1; i < C_; ++i) m = fmaxf(m, lg[i]);
            float sexp = 0.f;
            #pragma unroll
            for (int i = 0; i < C_; ++i) sexp += expf(lg[i] - m);
            ce_acc += -(lg[s_lbl[bk]] - m - logf(sexp));
        } else {
            neg_cnt += 1.0f;
            spn_acc += softplus_f(o);
        }
    };
    accumulate(valid0, bi0, db0, bk0, p0, o0, idx0);
    accumulate(valid1, bi1, db1, bk1, p1, o1, idx1);

    // block reduction of 6 values
    float v[6] = {pos_cnt, neg_cnt, box_acc, spp_acc, spn_acc, ce_acc};
    #pragma unroll
    for (int i = 0; i < 6; ++i) {
        float x = v[i];
        for (int s = 32; s; s >>= 1) x += __shfl_down(x, s, 64);
        v[i] = x;
    }
    if ((tid & 63) == 0) {
        const int w = tid >> 6;
        #pragma unroll
        for (int i = 0; i < 6; ++i) s_red[w][i] = v[i];
    }
    __syncthreads();
    if (tid == 0) {
        float s0 = s_red[0][0] + s_red[1][0] + s_red[2][0] + s_red[3][0];
        float s1 = s_red[0][1] + s_red[1][1] + s_red[2][1] + s_red[3][1];
        float s2 = s_red[0][2] + s_red[1][2] + s_red[2][2] + s_red[3][2];
        float s3 = s_red[0][3] + s_red[1][3] + s_red[2][3] + s_red[3][3];
        float s4 = s_red[0][4] + s_red[1][4] + s_red[2][4] + s_red[3][4];
        float s5 = s_red[0][5] + s_red[1][5] + s_red[2][5] + s_red[3][5];
        float4* outp = (float4*)(partials + (size_t)(cam * NCHUNK + chunk) * 8);
        outp[0] = make_float4(s0, s1, s2, s3);
        outp[1] = make_float4(s4, s5, 0.f, 0.f);
    }
}

// Phase 2: 240 threads (5 per cam, 10 records each, float4 loads) -> LDS
// reduce -> wave-0 shuffle reduce.
#define TPC 5
#define RPT (NCHUNK / TPC)    // 10
__global__ void yolo_phase2(const float* __restrict__ partials,
                            float* __restrict__ out)
{
    const int t = threadIdx.x;   // 0..255
    __shared__ float s_p[NCAMS * TPC][6];

    if (t < NCAMS * TPC) {
        const int cam = t / TPC;
        const int j   = t - cam * TPC;
        const float4* q = (const float4*)(partials +
                          ((size_t)cam * NCHUNK + j * RPT) * 8);
        float a0 = 0.f, a1 = 0.f, a2 = 0.f, a3 = 0.f, a4 = 0.f, a5 = 0.f;
        #pragma unroll
        for (int i = 0; i < RPT; ++i) {
            float4 x = q[2 * i];
            float4 y = q[2 * i + 1];
            a0 += x.x; a1 += x.y; a2 += x.z; a3 += x.w;
            a4 += y.x; a5 += y.y;
        }
        s_p[t][0] = a0; s_p[t][1] = a1; s_p[t][2] = a2;
        s_p[t][3] = a3; s_p[t][4] = a4; s_p[t][5] = a5;
    }
    __syncthreads();

    float box_sum = 0.f, obj_sum = 0.f, noobj_sum = 0.f, cls_sum = 0.f;
    float np_ = 0.f, nn_ = 0.f;
    if (t < NCAMS) {
        float p = 0.f, n = 0.f, bx = 0.f, sp = 0.f, sn = 0.f, ce = 0.f;
        #pragma unroll
        for (int j = 0; j < TPC; ++j) {
            p  += s_p[t * TPC + j][0];
            n  += s_p[t * TPC + j][1];
            bx += s_p[t * TPC + j][2];
            sp += s_p[t * TPC + j][3];
            sn += s_p[t * TPC + j][4];
            ce += s_p[t * TPC + j][5];
        }
        box_sum   = L_COORD * bx;
        obj_sum   = (p > 0.f) ? sp / fmaxf(p, 1.0f) : 0.f;
        cls_sum   = (p > 0.f) ? ce / fmaxf(p, 1.0f) : 0.f;
        noobj_sum = L_NOOBJ * ((n > 0.f) ? sn / fmaxf(n, 1.0f) : 0.f);
        np_ = p; nn_ = n;
    }
    if (t < 64) {   // cams 0..47 all live in wave 0
        for (int s = 32; s; s >>= 1) {
            box_sum   += __shfl_down(box_sum, s, 64);
            obj_sum   += __shfl_down(obj_sum, s, 64);
            noobj_sum += __shfl_down(noobj_sum, s, 64);
            cls_sum   += __shfl_down(cls_sum, s, 64);
            np_       += __shfl_down(np_, s, 64);
            nn_       += __shfl_down(nn_, s, 64);
        }
        if (t == 0) {
            const float box_loss   = (np_ > 0.f) ? box_sum / fmaxf(np_, 1.0f) : 0.f;
            const float obj_loss   = (np_ > 0.f) ? obj_sum / fmaxf(np_, 1.0f) : 0.f;
            const float cls_loss   = (np_ > 0.f) ? cls_sum / fmaxf(np_, 1.0f) : 0.f;
            const float noobj_loss = (nn_ > 0.f) ? noobj_sum / fmaxf(nn_, 1.0f) : 0.f;
            const float total = box_loss + obj_loss + noobj_loss + cls_loss;
            out[0] = total;
            out[1] = box_loss;
            out[2] = obj_loss;
            out[3] = noobj_loss;
            out[4] = cls_loss;
        }
    }
}

extern "C" void kernel_launch(void* const* d_in, const int* in_sizes, int n_in,
                              void* d_out, int out_size, void* d_ws, size_t ws_size,
                              hipStream_t stream) {
    const float* pred_boxes  = (const float*)d_in[0];
    const float* pred_labels = (const float*)d_in[1];
    const float* pred_obj    = (const float*)d_in[2];
    const float* gt_boxes    = (const float*)d_in[3];
    const int*   gt_labels   = (const int*)d_in[4];
    const int*   se          = (const int*)d_in[5];
    const int total_gt = in_sizes[3] / 4;

    float* partials = (float*)d_ws;   // NCAMS*NCHUNK*8 floats = 76.8 KB

    dim3 grid(NCHUNK, NCAMS);
    yolo_phase1<<<grid, BLOCK, 0, stream>>>(pred_boxes, pred_labels, pred_obj,
                                            gt_boxes, gt_labels, se,
                                            total_gt, partials);
    yolo_phase2<<<1, 256, 0, stream>>>(partials, (float*)d_out);
}